// Round 1
// baseline (100.040 us; speedup 1.0000x reference)
//
#include <hip/hip_runtime.h>
#include <hip/hip_bf16.h>

#define NQ     8
#define SEQL   128
#define BATCHN 256
#define EMBED  512
#define DIN    520          // EMBED + NQ
#define NROWS  (SEQL*BATCHN) // 32768
#define GSTR   32           // 4 gates * 8 qubits

// ---------------------------------------------------------------------------
// Kernel 1: G[row*32 + c] = dot(emb[sent[row]], W_c[0:512]) + b_c
//   row = t*256 + b ; c = g*8 + j ; W_c = row j of gate-g weight (8 x 520)
// Tile: 64 rows x 32 cols per block, K in chunks of 64.
// ---------------------------------------------------------------------------
__global__ __launch_bounds__(256, 2)
void k1_gates(const int* __restrict__ sent, const float* __restrict__ emb,
              const float* __restrict__ Wf, const float* __restrict__ Wi,
              const float* __restrict__ Wu, const float* __restrict__ Wo,
              const float* __restrict__ bf, const float* __restrict__ bi,
              const float* __restrict__ bu, const float* __restrict__ bo,
              float* __restrict__ G)
{
    __shared__ float Xs[64][68];   // 64 rows x 64 k (pad 68: 2-way max on reads)
    __shared__ float Ws[64][36];   // 64 k x 32 c (pad 36: conflict-free c-float4)
    __shared__ int   tok[64];

    const int tid  = threadIdx.x;
    const int row0 = blockIdx.x * 64;
    if (tid < 64) tok[tid] = sent[row0 + tid];

    const int rg = tid >> 3;   // 0..31 -> rows rg*2, rg*2+1
    const int cg = tid & 7;    // 0..7  -> cols cg*4 .. cg*4+3

    float acc0[4] = {0.f,0.f,0.f,0.f};
    float acc1[4] = {0.f,0.f,0.f,0.f};
    __syncthreads();

    for (int k0 = 0; k0 < EMBED; k0 += 64) {
        // stage X (gather): 64 rows x 64 floats = 1024 float4
        #pragma unroll
        for (int i = 0; i < 4; ++i) {
            int f4 = tid + i * 256;
            int r  = f4 >> 4, k4 = f4 & 15;
            float4 v = *reinterpret_cast<const float4*>(
                &emb[(size_t)tok[r] * EMBED + k0 + k4 * 4]);
            *reinterpret_cast<float4*>(&Xs[r][k4 * 4]) = v;
        }
        // stage W transposed: Ws[kk][c]
        #pragma unroll
        for (int i = 0; i < 8; ++i) {
            int idx = tid + i * 256;        // 0..2047
            int c   = idx >> 6, kk = idx & 63;
            int g = c >> 3, j = c & 7;
            const float* W = (g == 0) ? Wf : (g == 1) ? Wi : (g == 2) ? Wu : Wo;
            Ws[kk][c] = W[j * DIN + k0 + kk];
        }
        __syncthreads();
        #pragma unroll
        for (int kk4 = 0; kk4 < 16; ++kk4) {
            float4 x0 = *reinterpret_cast<const float4*>(&Xs[rg*2+0][kk4*4]);
            float4 x1 = *reinterpret_cast<const float4*>(&Xs[rg*2+1][kk4*4]);
            #pragma unroll
            for (int q = 0; q < 4; ++q) {
                float4 w = *reinterpret_cast<const float4*>(&Ws[kk4*4+q][cg*4]);
                float xa = (q==0)?x0.x:(q==1)?x0.y:(q==2)?x0.z:x0.w;
                float xb = (q==0)?x1.x:(q==1)?x1.y:(q==2)?x1.z:x1.w;
                acc0[0] += xa*w.x; acc0[1] += xa*w.y; acc0[2] += xa*w.z; acc0[3] += xa*w.w;
                acc1[0] += xb*w.x; acc1[1] += xb*w.y; acc1[2] += xb*w.z; acc1[3] += xb*w.w;
            }
        }
        __syncthreads();
    }

    // bias: c = cg*4+n -> g = cg>>1 (uniform per thread), j = (cg&1)*4+n
    const int   gq = cg >> 1;
    const float* B = (gq == 0) ? bf : (gq == 1) ? bi : (gq == 2) ? bu : bo;
    float b0 = B[(cg&1)*4+0], b1 = B[(cg&1)*4+1], b2 = B[(cg&1)*4+2], b3 = B[(cg&1)*4+3];

    float4 o0 = make_float4(acc0[0]+b0, acc0[1]+b1, acc0[2]+b2, acc0[3]+b3);
    float4 o1 = make_float4(acc1[0]+b0, acc1[1]+b1, acc1[2]+b2, acc1[3]+b3);
    size_t base = (size_t)(row0 + rg*2) * GSTR + cg*4;
    *reinterpret_cast<float4*>(&G[base])        = o0;
    *reinterpret_cast<float4*>(&G[base + GSTR]) = o1;
}

// ---------------------------------------------------------------------------
// Kernel 2: sequential LSTM recurrence with closed-form qlayer.
//   32 lanes per batch row: lane32 = g*8 + j. All comm intra-wave (shuffles).
//   qlayer: a = y + theta; cs = cos(a);
//     out_j = prod_{w<=j} cs_w (j>=1) ; out_0 = prod_{w=1..7} cs_w
// ---------------------------------------------------------------------------
__global__ __launch_bounds__(256)
void k2_lstm(const float* __restrict__ G,
             const float* __restrict__ Wf, const float* __restrict__ Wi,
             const float* __restrict__ Wu, const float* __restrict__ Wo,
             const float* __restrict__ thf, const float* __restrict__ thi,
             const float* __restrict__ thu, const float* __restrict__ tho,
             float* __restrict__ out)
{
    const int tid    = threadIdx.x;
    const int wlane  = tid & 63;
    const int base32 = wlane & 32;     // base lane of this row's 32-group in wave
    const int l32    = tid & 31;
    const int g      = l32 >> 3;       // gate 0..3 (f,i,u,o)
    const int j      = l32 & 7;        // qubit 0..7
    const int b      = blockIdx.x * 8 + (tid >> 5);

    const float* Wsel = (g==0) ? Wf  : (g==1) ? Wi  : (g==2) ? Wu  : Wo;
    const float* tsel = (g==0) ? thf : (g==1) ? thi : (g==2) ? thu : tho;

    float Wh[8];
    #pragma unroll
    for (int k = 0; k < 8; ++k) Wh[k] = Wsel[j * DIN + EMBED + k];
    const float th = tsel[j];

    float h[8] = {0.f,0.f,0.f,0.f,0.f,0.f,0.f,0.f};
    float c_own = 0.f, h_own = 0.f;
    const float* Gp = G + (size_t)b * GSTR + l32;

    for (int t = 0; t < SEQL; ++t) {
        float y = Gp[(size_t)t * (BATCHN*GSTR)];
        #pragma unroll
        for (int k = 0; k < 8; ++k) y += h[k] * Wh[k];
        float a  = y + th;
        float cs = __cosf(a);

        // inclusive prefix product over j within the 8-lane qubit group
        float p = cs, u;
        u = __shfl(p, (wlane - 1) & 63); if (j >= 1) p *= u;
        u = __shfl(p, (wlane - 2) & 63); if (j >= 2) p *= u;
        u = __shfl(p, (wlane - 4) & 63); if (j >= 4) p *= u;
        // full product excluding lane 0's cs (lane 0 contributes 1)
        float v = (j == 0) ? 1.0f : cs;
        v *= __shfl(v, wlane ^ 1);
        v *= __shfl(v, wlane ^ 2);
        v *= __shfl(v, wlane ^ 4);
        float qv = (j == 0) ? v : p;

        // gate nonlinearity, branchless: tanh(x) = 2*sigmoid(2x)-1
        float xq  = (g == 2) ? qv + qv : qv;
        float s   = 1.f / (1.f + __expf(-xq));
        float act = (g == 2) ? (s + s - 1.f) : s;

        // gather the four gate values for this qubit
        float fv = __shfl(act, base32 +      j);
        float iv = __shfl(act, base32 +  8 + j);
        float uv = __shfl(act, base32 + 16 + j);
        float ov = __shfl(act, base32 + 24 + j);

        c_own = fv * c_own + iv * uv;               // |c| <= 1/(1-sig(1)) ~ 3.7
        float e2 = __expf(c_own + c_own);
        float tc = (e2 - 1.f) / (e2 + 1.f);         // tanh(c)
        h_own = ov * tc;

        // rebroadcast h to all 32 lanes of the row
        #pragma unroll
        for (int k = 0; k < 8; ++k) h[k] = __shfl(h_own, base32 + k);
    }
    if (g == 0) out[b * NQ + j] = h_own;
}

// ---------------------------------------------------------------------------
extern "C" void kernel_launch(void* const* d_in, const int* in_sizes, int n_in,
                              void* d_out, int out_size, void* d_ws, size_t ws_size,
                              hipStream_t stream)
{
    const int*   sent = (const int*)  d_in[0];
    // d_in[1] = features : unused by the reference
    const float* emb  = (const float*)d_in[2];
    const float* Wf   = (const float*)d_in[3];
    const float* bf   = (const float*)d_in[4];
    const float* Wi   = (const float*)d_in[5];
    const float* bi   = (const float*)d_in[6];
    const float* Wu   = (const float*)d_in[7];
    const float* bu   = (const float*)d_in[8];
    const float* Wo   = (const float*)d_in[9];
    const float* bo   = (const float*)d_in[10];
    const float* thf  = (const float*)d_in[11];
    const float* thi  = (const float*)d_in[12];
    const float* thu  = (const float*)d_in[13];
    const float* tho  = (const float*)d_in[14];
    float* out = (float*)d_out;

    float* G = (float*)d_ws;   // 32768 * 32 * 4B = 4 MB

    k1_gates<<<NROWS/64, 256, 0, stream>>>(sent, emb, Wf, Wi, Wu, Wo,
                                           bf, bi, bu, bo, G);
    k2_lstm<<<BATCHN/8, 256, 0, stream>>>(G, Wf, Wi, Wu, Wo,
                                          thf, thi, thu, tho, out);
}

// Round 3
// 98.077 us; speedup vs baseline: 1.0200x; 1.0200x over previous
//
#include <hip/hip_runtime.h>
#include <hip/hip_bf16.h>

#define NQ     8
#define SEQL   128
#define BATCHN 256
#define EMBED  512
#define DIN    520          // EMBED + NQ
#define NROWS  (SEQL*BATCHN) // 32768
#define GSTR   32           // 4 gates * 8 qubits

// ---------------------------------------------------------------------------
// DPP helpers (VALU cross-lane within 16-lane rows)
//   row_shr:N -> lane i receives lane i-N (data moves to higher lanes)
//   row_shl:N -> lane i receives lane i+N
// ---------------------------------------------------------------------------
#define DPP_QP(a,b,c,d) ((a)|((b)<<2)|((c)<<4)|((d)<<6))
#define DPP_SHL(n) (0x100+(n))
#define DPP_SHR(n) (0x110+(n))

template<int CTRL>
__device__ __forceinline__ float updpf(float old_, float src) {
    return __int_as_float(__builtin_amdgcn_update_dpp(
        __float_as_int(old_), __float_as_int(src), CTRL, 0xF, 0xF, false));
}

// ---------------------------------------------------------------------------
// Kernel 1: G[row*32 + c] = dot(emb[sent[row]], W_c[0:512]) + b_c
//   row = t*256 + b ; c = g*8 + j. 128-row x 32-col tile, 16 outputs/thread.
// ---------------------------------------------------------------------------
__global__ __launch_bounds__(256, 2)
void k1_gates(const int* __restrict__ sent, const float* __restrict__ emb,
              const float* __restrict__ Wf, const float* __restrict__ Wi,
              const float* __restrict__ Wu, const float* __restrict__ Wo,
              const float* __restrict__ bf, const float* __restrict__ bi,
              const float* __restrict__ bu, const float* __restrict__ bo,
              float* __restrict__ G)
{
    __shared__ float Xs[128][68];   // 34.8 KB
    __shared__ float Ws[64][36];    // 9.2 KB
    __shared__ int   tok[128];

    const int tid  = threadIdx.x;
    const int row0 = blockIdx.x * 128;
    if (tid < 128) tok[tid] = sent[row0 + tid];

    const int rg = tid >> 3;   // 0..31 -> rows rg + 32*r
    const int cg = tid & 7;    // 0..7  -> cols cg*4 .. cg*4+3

    float acc[4][4] = {};
    __syncthreads();

    for (int k0 = 0; k0 < EMBED; k0 += 64) {
        // stage X (gather): 128 rows x 64 floats = 2048 float4
        #pragma unroll
        for (int i = 0; i < 8; ++i) {
            int f4 = tid + i * 256;
            int r  = f4 >> 4, k4 = f4 & 15;
            float4 v = *reinterpret_cast<const float4*>(
                &emb[(size_t)tok[r] * EMBED + k0 + k4 * 4]);
            *reinterpret_cast<float4*>(&Xs[r][k4 * 4]) = v;
        }
        // stage W transposed: Ws[kk][c]
        #pragma unroll
        for (int i = 0; i < 8; ++i) {
            int idx = tid + i * 256;        // 0..2047
            int c   = idx >> 6, kk = idx & 63;
            int g = c >> 3, j = c & 7;
            const float* W = (g == 0) ? Wf : (g == 1) ? Wi : (g == 2) ? Wu : Wo;
            Ws[kk][c] = W[j * DIN + k0 + kk];
        }
        __syncthreads();
        #pragma unroll
        for (int kk4 = 0; kk4 < 16; ++kk4) {
            float4 x0 = *reinterpret_cast<const float4*>(&Xs[rg +  0][kk4*4]);
            float4 x1 = *reinterpret_cast<const float4*>(&Xs[rg + 32][kk4*4]);
            float4 x2 = *reinterpret_cast<const float4*>(&Xs[rg + 64][kk4*4]);
            float4 x3 = *reinterpret_cast<const float4*>(&Xs[rg + 96][kk4*4]);
            #pragma unroll
            for (int q = 0; q < 4; ++q) {
                float4 w = *reinterpret_cast<const float4*>(&Ws[kk4*4+q][cg*4]);
                float e0 = (q==0)?x0.x:(q==1)?x0.y:(q==2)?x0.z:x0.w;
                float e1 = (q==0)?x1.x:(q==1)?x1.y:(q==2)?x1.z:x1.w;
                float e2 = (q==0)?x2.x:(q==1)?x2.y:(q==2)?x2.z:x2.w;
                float e3 = (q==0)?x3.x:(q==1)?x3.y:(q==2)?x3.z:x3.w;
                acc[0][0]+=e0*w.x; acc[0][1]+=e0*w.y; acc[0][2]+=e0*w.z; acc[0][3]+=e0*w.w;
                acc[1][0]+=e1*w.x; acc[1][1]+=e1*w.y; acc[1][2]+=e1*w.z; acc[1][3]+=e1*w.w;
                acc[2][0]+=e2*w.x; acc[2][1]+=e2*w.y; acc[2][2]+=e2*w.z; acc[2][3]+=e2*w.w;
                acc[3][0]+=e3*w.x; acc[3][1]+=e3*w.y; acc[3][2]+=e3*w.z; acc[3][3]+=e3*w.w;
            }
        }
        __syncthreads();
    }

    // bias: c = cg*4+n -> g = cg>>1 (uniform per thread), j = (cg&1)*4+n
    const int   gq = cg >> 1;
    const float* B = (gq == 0) ? bf : (gq == 1) ? bi : (gq == 2) ? bu : bo;
    float b0 = B[(cg&1)*4+0], b1 = B[(cg&1)*4+1], b2 = B[(cg&1)*4+2], b3 = B[(cg&1)*4+3];

    #pragma unroll
    for (int r = 0; r < 4; ++r) {
        float4 o = make_float4(acc[r][0]+b0, acc[r][1]+b1, acc[r][2]+b2, acc[r][3]+b3);
        size_t base = (size_t)(row0 + rg + 32*r) * GSTR + cg*4;
        *reinterpret_cast<float4*>(&G[base]) = o;
    }
}

// ---------------------------------------------------------------------------
// Kernel 2: sequential LSTM recurrence, closed-form qlayer, all-DPP comm.
//   16 lanes per batch row, lane m = l16&7 = qubit (lanes 8-15 mirror).
//   Each lane computes all 4 gates for its qubit -> gates are lane-local.
//   qlayer: cs = cos(y+theta); out_j = prod_{w<=j} cs_w (j>=1),
//           out_0 = prod_{w=1..7} cs_w.
//   m^4 exchange: m<4 needs lane m+4 -> row_shl:4 ; m>=4 needs m-4 -> row_shr:4
// ---------------------------------------------------------------------------
__global__ __launch_bounds__(64)
void k2_lstm(const float* __restrict__ G,
             const float* __restrict__ Wf, const float* __restrict__ Wi,
             const float* __restrict__ Wu, const float* __restrict__ Wo,
             const float* __restrict__ thf, const float* __restrict__ thi,
             const float* __restrict__ thu, const float* __restrict__ tho,
             float* __restrict__ out)
{
    const int tid = threadIdx.x;          // 0..63 (1 wave per block)
    const int l16 = tid & 15;
    const int m   = l16 & 7;              // qubit
    const int b   = blockIdx.x * 4 + (tid >> 4);

    const float* Wg[4] = {Wf, Wi, Wu, Wo};
    const float* tg[4] = {thf, thi, thu, tho};

    // permuted h-weights so that y_g = sum_r H[r]*Whp[g][r] with H[r]=h[m^r]
    float Whp[4][8], th[4];
    #pragma unroll
    for (int g = 0; g < 4; ++g) {
        th[g] = tg[g][m];
        #pragma unroll
        for (int r = 0; r < 8; ++r)
            Whp[g][r] = Wg[g][m * DIN + EMBED + (m ^ r)];
    }

    float H[8];
    #pragma unroll
    for (int r = 0; r < 8; ++r) H[r] = 0.f;
    float c_own = 0.f, h_own = 0.f;

    const float* Gp = G + (size_t)b * GSTR + m;
    // preload step 0 (theta folded in)
    float a0 = Gp[0] + th[0], a1 = Gp[8]  + th[1];
    float a2 = Gp[16]+ th[2], a3 = Gp[24] + th[3];

    const bool m1 = (m >= 1), m2 = (m >= 2), m4 = (m >= 4), mz = (m == 0);

    for (int t = 0; t < SEQL; ++t) {
        // prefetch next step's y (chain-independent; hides L2/L3 latency)
        int tn = (t + 1 < SEQL) ? t + 1 : t;
        const float* Gn = Gp + (size_t)tn * (BATCHN * GSTR);
        float n0 = Gn[0], n1 = Gn[8], n2 = Gn[16], n3 = Gn[24];

        float acc[4] = {a0, a1, a2, a3};
        #pragma unroll
        for (int g = 0; g < 4; ++g)
            #pragma unroll
            for (int r = 0; r < 8; ++r) acc[g] += H[r] * Whp[g][r];

        float qv[4];
        #pragma unroll
        for (int g = 0; g < 4; ++g) {
            float cs = __cosf(acc[g]);
            // inclusive prefix product over the 8-lane group (row_shr, guarded)
            float p = cs, s;
            s = updpf<DPP_SHR(1)>(1.0f, p); p *= (m1 ? s : 1.0f);
            s = updpf<DPP_SHR(2)>(1.0f, p); p *= (m2 ? s : 1.0f);
            s = updpf<DPP_SHR(4)>(1.0f, p); p *= (m4 ? s : 1.0f);
            // full product excluding lane 0's cs (butterfly)
            float v = mz ? 1.0f : cs;
            v *= updpf<DPP_QP(1,0,3,2)>(v, v);
            v *= updpf<DPP_QP(2,3,0,1)>(v, v);
            float xl = updpf<DPP_SHL(4)>(v, v);   // lane i <- i+4 (for m<4)
            float xr = updpf<DPP_SHR(4)>(v, v);   // lane i <- i-4 (for m>=4)
            v *= (m4 ? xr : xl);
            qv[g] = mz ? v : p;
        }

        // activations: f,i,o sigmoid; u tanh
        float fv = 1.f / (1.f + __expf(-qv[0]));
        float iv = 1.f / (1.f + __expf(-qv[1]));
        float su = 1.f / (1.f + __expf(-2.f * qv[2]));
        float uv = su + su - 1.f;
        float ov = 1.f / (1.f + __expf(-qv[3]));

        c_own = fv * c_own + iv * uv;
        float e2 = __expf(c_own + c_own);
        float tc = (e2 - 1.f) / (e2 + 1.f);       // tanh(c)
        h_own = ov * tc;

        // all-gather h across the 8-lane group: H[r] = h[m^r]
        H[0] = h_own;
        H[1] = updpf<DPP_QP(1,0,3,2)>(H[0], H[0]);
        H[2] = updpf<DPP_QP(2,3,0,1)>(H[0], H[0]);
        H[3] = updpf<DPP_QP(2,3,0,1)>(H[1], H[1]);
        #pragma unroll
        for (int r = 0; r < 4; ++r) {
            float xl = updpf<DPP_SHL(4)>(H[r], H[r]);  // for m<4: h[(m+4)^r]
            float xr = updpf<DPP_SHR(4)>(H[r], H[r]);  // for m>=4: h[(m-4)^r]
            H[4 + r] = m4 ? xr : xl;
        }

        a0 = n0 + th[0]; a1 = n1 + th[1]; a2 = n2 + th[2]; a3 = n3 + th[3];
    }

    if (l16 < 8) out[b * NQ + m] = h_own;
}

// ---------------------------------------------------------------------------
extern "C" void kernel_launch(void* const* d_in, const int* in_sizes, int n_in,
                              void* d_out, int out_size, void* d_ws, size_t ws_size,
                              hipStream_t stream)
{
    const int*   sent = (const int*)  d_in[0];
    // d_in[1] = features : unused by the reference
    const float* emb  = (const float*)d_in[2];
    const float* Wf   = (const float*)d_in[3];
    const float* bf   = (const float*)d_in[4];
    const float* Wi   = (const float*)d_in[5];
    const float* bi   = (const float*)d_in[6];
    const float* Wu   = (const float*)d_in[7];
    const float* bu   = (const float*)d_in[8];
    const float* Wo   = (const float*)d_in[9];
    const float* bo   = (const float*)d_in[10];
    const float* thf  = (const float*)d_in[11];
    const float* thi  = (const float*)d_in[12];
    const float* thu  = (const float*)d_in[13];
    const float* tho  = (const float*)d_in[14];
    float* out = (float*)d_out;

    float* G = (float*)d_ws;   // 32768 * 32 * 4B = 4 MB

    k1_gates<<<NROWS/128, 256, 0, stream>>>(sent, emb, Wf, Wi, Wu, Wo,
                                            bf, bi, bu, bo, G);
    k2_lstm<<<BATCHN/4, 64, 0, stream>>>(G, Wf, Wi, Wu, Wo,
                                         thf, thi, thu, tho, out);
}